// Round 3
// baseline (841.918 us; speedup 1.0000x reference)
//
#include <hip/hip_runtime.h>
#include <hip/hip_bf16.h>

typedef __attribute__((ext_vector_type(8))) short short8;
typedef __attribute__((ext_vector_type(4))) float floatx4;
typedef __attribute__((ext_vector_type(8))) unsigned short ushort8v;

#define N_DIM 12288
#define SPLITK 8
#define KCHUNK (N_DIM / SPLITK)   // 1536
#define NIT (KCHUNK / 64)         // 24 K-steps of 64

__device__ __forceinline__ unsigned short f2bf(float f) {
  union { float f; unsigned int i; } x; x.f = f;
  unsigned int r = x.i + 0x7fffu + ((x.i >> 16) & 1u);   // RNE
  return (unsigned short)(r >> 16);
}

// ---------------------------------------------------------------------------
// Kernel 1: phi += obs[64 x KCHUNK_s] @ W[KCHUNK_s x 12288]  (+bias when s==0)
// W streams global -> registers (B frag is k-major per lane: 16 coalesced
// dwords per K64-step, no LDS round-trip). A (L2-resident) staged bf16 in
// double-buffered LDS, 1 barrier/iter. Wave w owns n-cols [n0+16w, +16),
// all 64 m rows (4 m-tiles). grid=(192, 8), block=256.
// ---------------------------------------------------------------------------
__global__ __launch_bounds__(256) void gemm_phi(
    const float* __restrict__ obs, const float* __restrict__ W,
    const float* __restrict__ bias, float* __restrict__ phi)
{
  __shared__ unsigned short A_s[2][64 * 72];   // [m][k] bf16, stride 72

  const int t = threadIdx.x;
  const int n0 = blockIdx.x * 64;
  const int s  = blockIdx.y;
  const int k0 = s * KCHUNK;
  const int lane = t & 63, wv = t >> 6;
  const int l16 = lane & 15, q = lane >> 4;
  const int nc = n0 + 16 * wv + l16;           // this lane's B/C column

  floatx4 acc[4];
#pragma unroll
  for (int i = 0; i < 4; i++) acc[i] = (floatx4){0.f, 0.f, 0.f, 0.f};

  const int am = t >> 2, ak = (t & 3) * 16;    // A staging: row, 16-col group
  const float* Ap = obs + (size_t)am * N_DIM + k0 + ak;
  const float* Bp = W + (size_t)(k0 + 8 * q) * N_DIM + nc;  // rows k0+8q+..., col nc

  // ---- prologue: stage A(it=0) -> LDS buf0; load B(it=0) -> regs ----
  float fb[16];
  {
    floatx4 fA[4];
#pragma unroll
    for (int i = 0; i < 4; i++) fA[i] = *(const floatx4*)(Ap + 4 * i);
    ushort8v u0, u1;
#pragma unroll
    for (int i = 0; i < 4; i++) {
      u0[i] = f2bf(fA[0][i]); u0[4 + i] = f2bf(fA[1][i]);
      u1[i] = f2bf(fA[2][i]); u1[4 + i] = f2bf(fA[3][i]);
    }
    *(ushort8v*)&A_s[0][am * 72 + ak]     = u0;
    *(ushort8v*)&A_s[0][am * 72 + ak + 8] = u1;
#pragma unroll
    for (int kk = 0; kk < 2; ++kk)
#pragma unroll
      for (int j = 0; j < 8; ++j)
        fb[kk * 8 + j] = Bp[(size_t)(32 * kk + j) * N_DIM];
  }
  __syncthreads();

  // ---- main loop: 1 barrier/iter, next-iter loads in flight across it ----
#pragma unroll 2
  for (int it = 0; it < NIT; ++it) {
    const int cur = it & 1;
    const bool more = (it + 1 < NIT);
    floatx4 fA[4];
    float fbn[16];
    if (more) {
      const float* ap = Ap + (it + 1) * 64;
#pragma unroll
      for (int i = 0; i < 4; i++) fA[i] = *(const floatx4*)(ap + 4 * i);
      const float* bp = Bp + (size_t)(it + 1) * 64 * N_DIM;
#pragma unroll
      for (int kk = 0; kk < 2; ++kk)
#pragma unroll
        for (int j = 0; j < 8; ++j)
          fbn[kk * 8 + j] = bp[(size_t)(32 * kk + j) * N_DIM];
    }
    // convert current B regs -> bf16 frags (B[k][n]: n=l16, k=32kk+8q+j)
    short8 bfr0, bfr1;
#pragma unroll
    for (int j = 0; j < 8; ++j) {
      bfr0[j] = (short)f2bf(fb[j]);
      bfr1[j] = (short)f2bf(fb[8 + j]);
    }
    // 8 MFMAs on current A buffer (A[m][k]: m=16mt+l16, k=32kk+8q+j)
#pragma unroll
    for (int mt = 0; mt < 4; ++mt) {
      short8 af0 = *(const short8*)&A_s[cur][(16 * mt + l16) * 72 + 8 * q];
      acc[mt] = __builtin_amdgcn_mfma_f32_16x16x32_bf16(af0, bfr0, acc[mt], 0, 0, 0);
    }
#pragma unroll
    for (int mt = 0; mt < 4; ++mt) {
      short8 af1 = *(const short8*)&A_s[cur][(16 * mt + l16) * 72 + 32 + 8 * q];
      acc[mt] = __builtin_amdgcn_mfma_f32_16x16x32_bf16(af1, bfr1, acc[mt], 0, 0, 0);
    }
    if (more) {
      ushort8v u0, u1;
#pragma unroll
      for (int i = 0; i < 4; i++) {
        u0[i] = f2bf(fA[0][i]); u0[4 + i] = f2bf(fA[1][i]);
        u1[i] = f2bf(fA[2][i]); u1[4 + i] = f2bf(fA[3][i]);
      }
      *(ushort8v*)&A_s[cur ^ 1][am * 72 + ak]     = u0;
      *(ushort8v*)&A_s[cur ^ 1][am * 72 + ak + 8] = u1;
#pragma unroll
      for (int i = 0; i < 16; i++) fb[i] = fbn[i];
    }
    __syncthreads();
  }

  // epilogue: C/D col=l16 (-> nc), row=q*4+r within m-tile  [m89/m91]
  const float bv = (s == 0) ? bias[nc] : 0.f;
#pragma unroll
  for (int mt = 0; mt < 4; ++mt) {
#pragma unroll
    for (int r = 0; r < 4; ++r) {
      const int m = 16 * mt + 4 * q + r;
      atomicAdd(&phi[(size_t)m * N_DIM + nc], acc[mt][r] + bv);
    }
  }
}

// ---------------------------------------------------------------------------
// Kernel 2: per-batch softmax + K=64 VIN sweeps (ping-pong LDS) + argmax +
// patch + MLP. grid = 64 (one block per batch), block = 256 (4x4 cells/thread)
// ---------------------------------------------------------------------------
#define VSTR 76
#define VOFF(h, w) (((h) + 1) * VSTR + (w) + 4)  // halo grid, interior 16B-aligned

__global__ __launch_bounds__(256) void vin_mlp(
    const float* __restrict__ obs, const float* __restrict__ phi,
    const float* __restrict__ w1, const float* __restrict__ b1,
    const float* __restrict__ w2, const float* __restrict__ b2,
    float* __restrict__ out)
{
  __shared__ float Vb[2][66 * VSTR];
  __shared__ float red_v[256];
  __shared__ int   red_i[256];

  const int b = blockIdx.x;
  const int t = threadIdx.x;
  const int ty = t >> 4, tx = t & 15;
  const int h0 = ty * 4, w0 = tx * 4;

  for (int i = t; i < 2 * 66 * VSTR; i += 256) (&Vb[0][0])[i] = 0.f;

  float rin[16], rout[16], lg[16];
#pragma unroll
  for (int r = 0; r < 4; r++) {
    const int j = 3 * ((h0 + r) * 64 + w0);
    const floatx4* p4 = (const floatx4*)(phi + (size_t)b * N_DIM + j);
    floatx4 x0 = p4[0], x1 = p4[1], x2 = p4[2];
    float f[12];
#pragma unroll
    for (int c = 0; c < 4; c++) { f[c] = x0[c]; f[4 + c] = x1[c]; f[8 + c] = x2[c]; }
#pragma unroll
    for (int c = 0; c < 4; c++) {
      rin [r * 4 + c] = f[3 * c + 0];
      rout[r * 4 + c] = f[3 * c + 1];
      lg  [r * 4 + c] = f[3 * c + 2];
    }
  }

  float lmax = -3.4e38f;
#pragma unroll
  for (int i = 0; i < 16; i++) lmax = fmaxf(lmax, lg[i]);
  __syncthreads();
  red_v[t] = lmax; __syncthreads();
  for (int o = 128; o > 0; o >>= 1) { if (t < o) red_v[t] = fmaxf(red_v[t], red_v[t + o]); __syncthreads(); }
  const float M = red_v[0];
  __syncthreads();
  float p[16]; float esum = 0.f;
#pragma unroll
  for (int i = 0; i < 16; i++) { p[i] = __expf(lg[i] - M); esum += p[i]; }
  red_v[t] = esum; __syncthreads();
  for (int o = 128; o > 0; o >>= 1) { if (t < o) red_v[t] += red_v[t + o]; __syncthreads(); }
  const float inv = 1.f / red_v[0];
  __syncthreads();
#pragma unroll
  for (int i = 0; i < 16; i++) p[i] *= inv;

#pragma unroll
  for (int r = 0; r < 4; r++) {
    floatx4 rr = { rin[r * 4 + 0], rin[r * 4 + 1], rin[r * 4 + 2], rin[r * 4 + 3] };
    *(floatx4*)&Vb[1][VOFF(h0 + r, w0)] = rr;
  }
  __syncthreads();
  float cu[16], cdn[16], cl[16], cr[16];
#pragma unroll
  for (int r = 0; r < 4; r++) {
#pragma unroll
    for (int c = 0; c < 4; c++) {
      const int i = r * 4 + c, h = h0 + r, w = w0 + c;
      const float nu = Vb[1][VOFF(h - 1, w)];
      const float nd = Vb[1][VOFF(h + 1, w)];
      const float nl = Vb[1][VOFF(h, w - 1)];
      const float nr = Vb[1][VOFF(h, w + 1)];
      cu [i] = nu - (nu != 0.f ? rout[i] : 0.f);
      cdn[i] = nd - (nd != 0.f ? rout[i] : 0.f);
      cl [i] = nl - (nl != 0.f ? rout[i] : 0.f);
      cr [i] = nr - (nr != 0.f ? rout[i] : 0.f);
    }
  }
  __syncthreads();

  float v[16];
#pragma unroll
  for (int i = 0; i < 16; i++) v[i] = 0.f;

  for (int k = 0; k < 64; k++) {
    const float* Vc = Vb[k & 1];
    float* Vn = Vb[(k & 1) ^ 1];
    const floatx4 top = *(const floatx4*)&Vc[VOFF(h0 - 1, w0)];
    const floatx4 bot = *(const floatx4*)&Vc[VOFF(h0 + 4, w0)];
    float lf[4], rt[4];
#pragma unroll
    for (int r = 0; r < 4; r++) { lf[r] = Vc[VOFF(h0 + r, w0 - 1)]; rt[r] = Vc[VOFF(h0 + r, w0 + 4)]; }
    float nv[16];
#pragma unroll
    for (int r = 0; r < 4; r++) {
#pragma unroll
      for (int c = 0; c < 4; c++) {
        const int i = r * 4 + c;
        const float vu = (r == 0) ? top[c] : v[i - 4];
        const float vd = (r == 3) ? bot[c] : v[i + 4];
        const float vl = (c == 0) ? lf[r] : v[i - 1];
        const float vr = (c == 3) ? rt[r] : v[i + 1];
        const float m1 = fmaxf(fmaf(p[i], vu, cu[i]), fmaf(p[i], vd, cdn[i]));
        const float m2 = fmaxf(fmaf(p[i], vl, cl[i]), fmaf(p[i], vr, cr[i]));
        nv[i] = fmaxf(v[i], fmaxf(m1, m2));
      }
    }
#pragma unroll
    for (int r = 0; r < 4; r++) {
      floatx4 w4 = { nv[r * 4 + 0], nv[r * 4 + 1], nv[r * 4 + 2], nv[r * 4 + 3] };
      *(floatx4*)&Vn[VOFF(h0 + r, w0)] = w4;
    }
#pragma unroll
    for (int i = 0; i < 16; i++) v[i] = nv[i];
    __syncthreads();
  }

  float amax = -3.4e38f; int aidx = 0;
#pragma unroll
  for (int r = 0; r < 4; r++) {
#pragma unroll
    for (int c = 0; c < 4; c++) {
      const int cell = (h0 + r) * 64 + (w0 + c);
      const float val = obs[(size_t)b * N_DIM + 3 * cell + 1];
      if (val > amax) { amax = val; aidx = cell; }
    }
  }
  red_v[t] = amax; red_i[t] = aidx;
  __syncthreads();
  for (int o = 128; o > 0; o >>= 1) {
    if (t < o) {
      const float v2 = red_v[t + o]; const int i2 = red_i[t + o];
      if (v2 > red_v[t] || (v2 == red_v[t] && i2 < red_i[t])) { red_v[t] = v2; red_i[t] = i2; }
    }
    __syncthreads();
  }
  const int pos = red_i[0];
  const int pi = pos >> 6, pj = pos & 63;
  __syncthreads();

  if (t < 36) {
    const int di = t / 12, rem = t % 12, dj = rem / 4, c4 = rem & 3;
    const int hh = pi - 1 + di, ww = pj - 1 + dj;
    float pv;
    if (c4 < 3) {
      pv = (hh >= 0 && hh < 64 && ww >= 0 && ww < 64)
           ? obs[(size_t)b * N_DIM + 3 * (hh * 64 + ww) + c4] : 0.f;
    } else {
      pv = Vb[0][VOFF(hh, ww)];
    }
    red_v[t] = pv;
  }
  __syncthreads();
  if (t < 16) {
    float a = b1[t];
#pragma unroll
    for (int j = 0; j < 36; j++) a = fmaf(red_v[j], w1[j * 16 + t], a);
    red_v[64 + t] = fmaxf(a, 0.f);
  }
  __syncthreads();
  if (t < 4) {
    float a = b2[t];
#pragma unroll
    for (int i = 0; i < 16; i++) a = fmaf(red_v[64 + i], w2[i * 4 + t], a);
    out[b * 4 + t] = a;
  }
}

extern "C" void kernel_launch(void* const* d_in, const int* in_sizes, int n_in,
                              void* d_out, int out_size, void* d_ws, size_t ws_size,
                              hipStream_t stream)
{
  (void)in_sizes; (void)n_in; (void)out_size; (void)ws_size;
  const float* obs  = (const float*)d_in[0];
  const float* phiw = (const float*)d_in[1];
  const float* phib = (const float*)d_in[2];
  const float* w1   = (const float*)d_in[3];
  const float* b1   = (const float*)d_in[4];
  const float* w2   = (const float*)d_in[5];
  const float* b2   = (const float*)d_in[6];
  float* phi = (float*)d_ws;            // 64 * 12288 fp32 = 3.1 MB scratch
  float* out = (float*)d_out;

  hipMemsetAsync(phi, 0, (size_t)64 * N_DIM * sizeof(float), stream);
  hipLaunchKernelGGL(gemm_phi, dim3(N_DIM / 64, SPLITK), dim3(256), 0, stream,
                     obs, phiw, phib, phi);
  hipLaunchKernelGGL(vin_mlp, dim3(64), dim3(256), 0, stream,
                     obs, phi, w1, b1, w2, b2, out);
}